// Round 7
// baseline (659.443 us; speedup 1.0000x reference)
//
#include <hip/hip_runtime.h>

typedef __bf16 bf16;
typedef __bf16 bf16x4 __attribute__((ext_vector_type(4)));
typedef __bf16 bf16x8 __attribute__((ext_vector_type(8)));
typedef float  f32x4  __attribute__((ext_vector_type(4)));

#define TOKENS 16384
#define D_IN   4096
#define D_OUT  4096
#define RANK   512

// ---------------------------------------------------------------------------
// Prep 1: Vst[r][k] = bf16(V[k][r] * sigma[r])  (plain layout — flat GEMM reads
//   fragments directly from global, no LDS, so no swizzle wanted)
// ---------------------------------------------------------------------------
__global__ __launch_bounds__(256) void vt_scale(const float* __restrict__ V,
                                                const float* __restrict__ sg,
                                                bf16* __restrict__ Vst) {
    __shared__ float tile[64][65];
    const int tx = threadIdx.x & 63;
    const int ty = threadIdx.x >> 6;
    const int kb = blockIdx.x * 64;
    const int rb = blockIdx.y * 64;
    const float s = sg[rb + tx];
#pragma unroll
    for (int i = ty; i < 64; i += 4)
        tile[i][tx] = V[(size_t)(kb + i) * RANK + rb + tx] * s;
    __syncthreads();
#pragma unroll
    for (int i = ty; i < 64; i += 4)
        Vst[(size_t)(rb + i) * D_IN + kb + tx] = (bf16)tile[tx][i];
}

// ---------------------------------------------------------------------------
// Prep 2: elementwise f32 -> bf16
// ---------------------------------------------------------------------------
__global__ __launch_bounds__(256) void cvt_bf16_4(const float* __restrict__ in,
                                                  bf16* __restrict__ o, int n4) {
    int i = blockIdx.x * 256 + threadIdx.x;
    if (i < n4) {
        f32x4 v = *(const f32x4*)(in + (size_t)i * 4);
        bf16x4 b = { (bf16)v[0], (bf16)v[1], (bf16)v[2], (bf16)v[3] };
        *(bf16x4*)(o + (size_t)i * 4) = b;
    }
}

__device__ inline bf16x8 cvt8(f32x4 a, f32x4 b) {
    bf16x8 r;
    r[0] = (bf16)a[0]; r[1] = (bf16)a[1]; r[2] = (bf16)a[2]; r[3] = (bf16)a[3];
    r[4] = (bf16)b[0]; r[5] = (bf16)b[1]; r[6] = (bf16)b[2]; r[7] = (bf16)b[3];
    return r;
}

// ---------------------------------------------------------------------------
// FLAT GEMM (no LDS, no barriers): C[M][N] = A[M][K] @ B[N][K]^T.
//   128x128 block, 4 waves (2x2), wave 64x64 = 4x4 frags of 16x16x32 bf16.
//   Fragments are loaded DIRECTLY from global in MFMA layout: per instr a wave
//   touches 16 rows x 64B = full cache lines. B (and bf16-A) frag loads are
//   register double-buffered one K-step ahead; f32-A uses one f32 stage + cvt
//   at step end (keeps VGPR < 256). Latency hidden by dataflow + 8 waves/CU,
//   with zero LDS-pipe traffic (the r1-r6-invariant bottleneck).
// ---------------------------------------------------------------------------
template <bool AF32, bool OUTBF16>
__global__ __launch_bounds__(256) void gemm_flat(const void* __restrict__ A_,
                                                 const bf16* __restrict__ B,
                                                 void* __restrict__ out_,
                                                 int M, int N, int K) {
    const int t  = threadIdx.x;
    const int l  = t & 63;
    const int w  = t >> 6;
    const int wr = w >> 1, wc = w & 1;
    const int lr = l & 15;
    const int kg = l >> 4;
    const int kme = kg * 8;

    // XCD-aware bijective swizzle (nwg % 8 == 0). Chunked: consecutive swz
    // (same A-row panel, varying tn) land on the same XCD -> L2 reuse.
    const int nwg = gridDim.x;
    const int bid = blockIdx.x;
    const int cpx = nwg >> 3;
    const int swz = (bid & 7) * cpx + (bid >> 3);
    const int ntn = N >> 7;
    const int tm  = (swz / ntn) << 7;
    const int tn  = (swz % ntn) << 7;

    const float* Af = (const float*)A_;
    const bf16*  Ab = (const bf16*)A_;

    size_t aoff[4], boff[4];
#pragma unroll
    for (int f = 0; f < 4; ++f) {
        aoff[f] = (size_t)(tm + wr * 64 + f * 16 + lr) * K;
        boff[f] = (size_t)(tn + wc * 64 + f * 16 + lr) * K;
    }

    f32x4 acc[4][4] = {};

    // stages
    f32x4  sa32[4][2][2];          // AF32: one f32 stage (cvt'd at step end)
    bf16x8 afr[4][2];              // AF32: current A frags
    bf16x8 sa0[4][2], sa1[4][2];   // !AF32: two A stages
    bf16x8 sb0[4][2], sb1[4][2];   // two B stages

#define LD_B(SB, KT)                                                          \
    _Pragma("unroll") for (int f = 0; f < 4; ++f)                             \
    _Pragma("unroll") for (int ks = 0; ks < 2; ++ks)                          \
        SB[f][ks] = *(const bf16x8*)(B + boff[f] + (KT) + ks * 32 + kme);

#define LD_A32(KT)                                                            \
    _Pragma("unroll") for (int f = 0; f < 4; ++f)                             \
    _Pragma("unroll") for (int ks = 0; ks < 2; ++ks)                          \
    _Pragma("unroll") for (int h = 0; h < 2; ++h)                             \
        sa32[f][ks][h] = *(const f32x4*)(Af + aoff[f] + (KT) + ks * 32 + kme + h * 4);

#define CVT_A()                                                               \
    _Pragma("unroll") for (int f = 0; f < 4; ++f)                             \
    _Pragma("unroll") for (int ks = 0; ks < 2; ++ks)                          \
        afr[f][ks] = cvt8(sa32[f][ks][0], sa32[f][ks][1]);

#define LD_A16(SA, KT)                                                        \
    _Pragma("unroll") for (int f = 0; f < 4; ++f)                             \
    _Pragma("unroll") for (int ks = 0; ks < 2; ++ks)                          \
        SA[f][ks] = *(const bf16x8*)(Ab + aoff[f] + (KT) + ks * 32 + kme);

#define COMPUTE(AF, SB)                                                       \
    _Pragma("unroll") for (int ks = 0; ks < 2; ++ks)                          \
    _Pragma("unroll") for (int fm = 0; fm < 4; ++fm)                          \
    _Pragma("unroll") for (int fn = 0; fn < 4; ++fn)                          \
        acc[fm][fn] = __builtin_amdgcn_mfma_f32_16x16x32_bf16(                \
            AF[fm][ks], SB[fn][ks], acc[fm][fn], 0, 0, 0);

    const int NT = K >> 6;   // even (64 or 8)

    if constexpr (AF32) {
        LD_A32(0); LD_B(sb0, 0);
        CVT_A();                                    // waits tile-0 A
        for (int i = 0; i < NT; i += 2) {
            LD_A32((i + 1) * 64); LD_B(sb1, (i + 1) * 64);
            COMPUTE(afr, sb0);
            CVT_A();                                // frags for i+1
            if (i + 2 < NT) { LD_A32((i + 2) * 64); LD_B(sb0, (i + 2) * 64); }
            COMPUTE(afr, sb1);
            if (i + 2 < NT) CVT_A();                // frags for i+2
        }
    } else {
        LD_A16(sa0, 0); LD_B(sb0, 0);
        for (int i = 0; i < NT; i += 2) {
            LD_A16(sa1, (i + 1) * 64); LD_B(sb1, (i + 1) * 64);
            COMPUTE(sa0, sb0);
            if (i + 2 < NT) { LD_A16(sa0, (i + 2) * 64); LD_B(sb0, (i + 2) * 64); }
            COMPUTE(sa1, sb1);
        }
    }

    // ---- C-write: col = lane&15, row = (lane>>4)*4 + reg ----
    const int r0 = tm + wr * 64 + kg * 4;
    const int c0 = tn + wc * 64 + lr;
#pragma unroll
    for (int fm = 0; fm < 4; ++fm)
#pragma unroll
        for (int fn = 0; fn < 4; ++fn)
#pragma unroll
            for (int r = 0; r < 4; ++r) {
                size_t idx = (size_t)(r0 + fm * 16 + r) * N + (c0 + fn * 16);
                if constexpr (OUTBF16) ((bf16*)out_)[idx]  = (bf16)acc[fm][fn][r];
                else                   ((float*)out_)[idx] = acc[fm][fn][r];
            }
#undef LD_B
#undef LD_A32
#undef CVT_A
#undef LD_A16
#undef COMPUTE
}

// ---------------------------------------------------------------------------
extern "C" void kernel_launch(void* const* d_in, const int* in_sizes, int n_in,
                              void* d_out, int out_size, void* d_ws, size_t ws_size,
                              hipStream_t stream) {
    const float* x  = (const float*)d_in[0];  // [16384][4096]
    const float* U  = (const float*)d_in[1];  // [4096][512]
    const float* sg = (const float*)d_in[2];  // [512]
    const float* V  = (const float*)d_in[3];  // [4096][512]
    float* out = (float*)d_out;               // [16384][4096] f32

    char* ws = (char*)d_ws;
    bf16* Vst = (bf16*)ws;                    // [512][4096]  = 4 MB
    bf16* Ub  = (bf16*)(ws + (4u << 20));     // [4096][512]  = 4 MB
    bf16* T   = (bf16*)(ws + (8u << 20));     // [16384][512] = 16 MB

    vt_scale<<<dim3(D_IN / 64, RANK / 64), 256, 0, stream>>>(V, sg, Vst);
    cvt_bf16_4<<<(D_OUT * RANK / 4 + 255) / 256, 256, 0, stream>>>(U, Ub, D_OUT * RANK / 4);

    // GEMM1: T = bf16( x @ Vst^T ), flat, grid 512
    gemm_flat<true, true><<<(TOKENS / 128) * (RANK / 128), 256, 0, stream>>>(
        x, Vst, T, TOKENS, RANK, D_IN);

    // GEMM2: out = T @ Ub^T (f32), flat, grid 4096
    gemm_flat<false, false><<<(TOKENS / 128) * (D_OUT / 128), 256, 0, stream>>>(
        T, Ub, out, TOKENS, D_OUT, RANK);
}

// Round 8
// 264.593 us; speedup vs baseline: 2.4923x; 2.4923x over previous
//
#include <hip/hip_runtime.h>

typedef __bf16 bf16;
typedef __bf16 bf16x4 __attribute__((ext_vector_type(4)));
typedef __bf16 bf16x8 __attribute__((ext_vector_type(8)));
typedef float  f32x4  __attribute__((ext_vector_type(4)));

#define TOKENS 16384
#define D_IN   4096
#define D_OUT  4096
#define RANK   512

// Async global->LDS, 16B per lane. LDS dest must be wave-uniform base + lane*16;
// global SOURCE is per-lane (swizzles are applied by permuting the source).
__device__ inline void gload_lds16(const void* g, void* l) {
    __builtin_amdgcn_global_load_lds((const __attribute__((address_space(1))) void*)g,
                                     (__attribute__((address_space(3))) void*)l,
                                     16, 0, 0);
}

// ---------------------------------------------------------------------------
// Prep 1: Vst[r][k'] = bf16(V[k][r] * sigma[r]), PRE-SWIZZLED (verified r3/r4:
//   conflicts -> 0). Within each 64-k block: k -> k ^ ((r&7)<<3).
// ---------------------------------------------------------------------------
__global__ __launch_bounds__(256) void vt_scale(const float* __restrict__ V,
                                                const float* __restrict__ sg,
                                                bf16* __restrict__ Vst) {
    __shared__ float tile[64][65];
    const int tx = threadIdx.x & 63;
    const int ty = threadIdx.x >> 6;
    const int kb = blockIdx.x * 64;
    const int rb = blockIdx.y * 64;
    const float s = sg[rb + tx];
#pragma unroll
    for (int i = ty; i < 64; i += 4)
        tile[i][tx] = V[(size_t)(kb + i) * RANK + rb + tx] * s;
    __syncthreads();
#pragma unroll
    for (int i = ty; i < 64; i += 4) {
        int r = rb + i;
        int kp = kb + (tx ^ ((r & 7) << 3));
        Vst[(size_t)r * D_IN + kp] = (bf16)tile[tx][i];
    }
}

// ---------------------------------------------------------------------------
// Prep 2: elementwise f32 -> bf16
// ---------------------------------------------------------------------------
__global__ __launch_bounds__(256) void cvt_bf16_4(const float* __restrict__ in,
                                                  bf16* __restrict__ o, int n4) {
    int i = blockIdx.x * 256 + threadIdx.x;
    if (i < n4) {
        f32x4 v = *(const f32x4*)(in + (size_t)i * 4);
        bf16x4 b = { (bf16)v[0], (bf16)v[1], (bf16)v[2], (bf16)v[3] };
        *(bf16x4*)(o + (size_t)i * 4) = b;
    }
}

__device__ inline bf16x8 cvt8(f32x4 a, f32x4 b) {
    bf16x8 r;
    r[0] = (bf16)a[0]; r[1] = (bf16)a[1]; r[2] = (bf16)a[2]; r[3] = (bf16)a[3];
    r[4] = (bf16)b[0]; r[5] = (bf16)b[1]; r[6] = (bf16)b[2]; r[7] = (bf16)b[3];
    return r;
}

// ---------------------------------------------------------------------------
// GEMM1: T = bf16( A_f32 @ B_bf16^T ).  m97 2-barrier loop, 128x128, BK=64,
//   but A is staged as *f32 directly* via global_load_lds (8 DMAs/thread; no
//   VGPR round-trip, no ds_write, no cvt in the staging path — the r1-r7
//   bottleneck). Conversion happens at fragment read: 2x ds_read_b128 f32 +
//   cvt8, overlapping MFMA on the VALU pipe.
//   A chunk-swizzle (16B chunk c of row r holds global chunk c^(r&15)) is
//   applied on the per-lane GLOBAL SOURCE address; read inverts it. This
//   spreads each wave frag-read uniformly: 8 words/bank = conflict-free.
// ---------------------------------------------------------------------------
__global__ __launch_bounds__(256) void gemm1_alds(const float* __restrict__ A,
                                                  const bf16* __restrict__ B,
                                                  bf16* __restrict__ T,
                                                  int M, int N, int K) {
    __shared__ float Afl[128 * 64];   // 32 KB f32 A tile (chunk-swizzled)
    __shared__ bf16  Bl[128 * 64];    // 16 KB bf16 B tile (swizzled via source)

    const int t  = threadIdx.x;
    const int l  = t & 63;
    const int w  = t >> 6;
    const int wr = w >> 1, wc = w & 1;
    const int lr = l & 15;
    const int kg = l >> 4;
    const int sxorB = (lr & 7) << 3;     // B frag-read swizzle (elements)

    // XCD-aware bijective swizzle (nwg=512, %8==0)
    const int nwg = gridDim.x;
    const int bid = blockIdx.x;
    const int cpx = nwg >> 3;
    const int swz = (bid & 7) * cpx + (bid >> 3);
    const int ntn = N >> 7;
    const int tm  = (swz / ntn) << 7;
    const int tn  = (swz % ntn) << 7;

    // A staging: j = c*256+t -> row = c*16 + (t>>4), chunk-in-row = t&15.
    // row&15 == t>>4 for all c, so the source chunk swizzle is constant:
    const int arow = t >> 4;             // 0..15
    const int acr  = t & 15;
    const float* Asrc = A + (size_t)(tm + arow) * K + ((acr ^ arow) << 2);
    // B staging: row = c*32 + (t>>3), chunk t&7 (source pre-swizzled in Vst)
    const bf16* Bp = B + (size_t)(tn + (t >> 3)) * K + (t & 7) * 8;

    f32x4 acc[4][4] = {};

    for (int kt = 0; kt < K; kt += 64) {
        // ---- stage both tiles purely via async DMA (no reg transit) ----
#pragma unroll
        for (int c = 0; c < 8; ++c)
            gload_lds16(Asrc + kt + (size_t)(c * 16) * K, &Afl[(c * 256 + t) * 4]);
#pragma unroll
        for (int c = 0; c < 4; ++c)
            gload_lds16(Bp + kt + (size_t)(c * 32) * K, &Bl[(c * 256 + t) * 8]);
        __syncthreads();

#pragma unroll
        for (int ks = 0; ks < 2; ++ks) {
            bf16x8 af[4], bfr[4];
            const int q0 = ks * 8 + kg * 2;          // first 16B chunk of frag
#pragma unroll
            for (int f = 0; f < 4; ++f) {
                const float* Arow = &Afl[(wr * 64 + f * 16 + lr) * 64];
                f32x4 h0 = *(const f32x4*)&Arow[(q0 ^ lr) << 2];
                f32x4 h1 = *(const f32x4*)&Arow[((q0 + 1) ^ lr) << 2];
                af[f] = cvt8(h0, h1);
                bfr[f] = *(const bf16x8*)&Bl[(wc * 64 + f * 16 + lr) * 64 +
                                             ((ks * 32 + kg * 8) ^ sxorB)];
            }
#pragma unroll
            for (int fm = 0; fm < 4; ++fm)
#pragma unroll
                for (int fn = 0; fn < 4; ++fn)
                    acc[fm][fn] = __builtin_amdgcn_mfma_f32_16x16x32_bf16(
                        af[fm], bfr[fn], acc[fm][fn], 0, 0, 0);
        }
        __syncthreads();
    }

    // ---- C-write: col = lane&15, row = (lane>>4)*4 + reg ----
    const int r0 = tm + wr * 64 + kg * 4;
    const int c0 = tn + wc * 64 + lr;
#pragma unroll
    for (int fm = 0; fm < 4; ++fm)
#pragma unroll
        for (int fn = 0; fn < 4; ++fn)
#pragma unroll
            for (int r = 0; r < 4; ++r)
                T[(size_t)(r0 + fm * 16 + r) * N + (c0 + fn * 16)] = (bf16)acc[fm][fn][r];
}

// ---------------------------------------------------------------------------
// GEMM2 (r4 control, byte-identical): C_f32 = A_bf16 @ B_bf16^T, 128x128.
// ---------------------------------------------------------------------------
__global__ __launch_bounds__(256) void gemm2_bt(const bf16* __restrict__ A,
                                                const bf16* __restrict__ B,
                                                float* __restrict__ out,
                                                int M, int N, int K) {
    __shared__ bf16 Al[128 * 64];
    __shared__ bf16 Bl[128 * 64];

    const int t  = threadIdx.x;
    const int l  = t & 63;
    const int w  = t >> 6;
    const int wr = w >> 1, wc = w & 1;
    const int lr = l & 15;
    const int kg = l >> 4;

    const int nwg = gridDim.x;
    const int bid = blockIdx.x;
    const int cpx = nwg >> 3;
    const int swz = (bid & 7) * cpx + (bid >> 3);
    const int ntn = N >> 7;
    const int tm  = (swz / ntn) << 7;
    const int tn  = (swz % ntn) << 7;

    f32x4 acc[4][4] = {};

    for (int kt = 0; kt < K; kt += 64) {
#pragma unroll
        for (int c = 0; c < 4; ++c) {
            int i = c * 256 + t;
            gload_lds16(A + (size_t)(tm + (i >> 3)) * K + kt + (i & 7) * 8, &Al[i * 8]);
        }
#pragma unroll
        for (int c = 0; c < 4; ++c) {
            int i = c * 256 + t;
            gload_lds16(B + (size_t)(tn + (i >> 3)) * K + kt + (i & 7) * 8, &Bl[i * 8]);
        }
        __syncthreads();

#pragma unroll
        for (int ks = 0; ks < 2; ++ks) {
            bf16x8 af[4], bfr[4];
#pragma unroll
            for (int f = 0; f < 4; ++f) {
                af[f]  = *(const bf16x8*)&Al[(wr * 64 + f * 16 + lr) * 64 + ks * 32 + kg * 8];
                bfr[f] = *(const bf16x8*)&Bl[(wc * 64 + f * 16 + lr) * 64 + ks * 32 + kg * 8];
            }
#pragma unroll
            for (int fm = 0; fm < 4; ++fm)
#pragma unroll
                for (int fn = 0; fn < 4; ++fn)
                    acc[fm][fn] = __builtin_amdgcn_mfma_f32_16x16x32_bf16(
                        af[fm], bfr[fn], acc[fm][fn], 0, 0, 0);
        }
        __syncthreads();
    }

    const int r0 = tm + wr * 64 + kg * 4;
    const int c0 = tn + wc * 64 + lr;
#pragma unroll
    for (int fm = 0; fm < 4; ++fm)
#pragma unroll
        for (int fn = 0; fn < 4; ++fn)
#pragma unroll
            for (int r = 0; r < 4; ++r)
                out[(size_t)(r0 + fm * 16 + r) * N + (c0 + fn * 16)] = acc[fm][fn][r];
}

// ---------------------------------------------------------------------------
extern "C" void kernel_launch(void* const* d_in, const int* in_sizes, int n_in,
                              void* d_out, int out_size, void* d_ws, size_t ws_size,
                              hipStream_t stream) {
    const float* x  = (const float*)d_in[0];  // [16384][4096]
    const float* U  = (const float*)d_in[1];  // [4096][512]
    const float* sg = (const float*)d_in[2];  // [512]
    const float* V  = (const float*)d_in[3];  // [4096][512]
    float* out = (float*)d_out;               // [16384][4096] f32

    char* ws = (char*)d_ws;
    bf16* Vst = (bf16*)ws;                    // [512][4096]  = 4 MB (pre-swizzled)
    bf16* Ub  = (bf16*)(ws + (4u << 20));     // [4096][512]  = 4 MB
    bf16* T   = (bf16*)(ws + (8u << 20));     // [16384][512] = 16 MB

    vt_scale<<<dim3(D_IN / 64, RANK / 64), 256, 0, stream>>>(V, sg, Vst);
    cvt_bf16_4<<<(D_OUT * RANK / 4 + 255) / 256, 256, 0, stream>>>(U, Ub, D_OUT * RANK / 4);

    // GEMM1: T = bf16( x @ Vst^T ), A staged f32 via global_load_lds, grid 512
    gemm1_alds<<<(TOKENS / 128) * (RANK / 128), 256, 0, stream>>>(
        x, Vst, T, TOKENS, RANK, D_IN);

    // GEMM2: out = T @ Ub^T (f32 out), grid 4096
    gemm2_bt<<<(TOKENS / 128) * (D_OUT / 128), 256, 0, stream>>>(
        T, Ub, out, TOKENS, D_OUT, RANK);
}

// Round 9
// 252.070 us; speedup vs baseline: 2.6161x; 1.0497x over previous
//
#include <hip/hip_runtime.h>

typedef __bf16 bf16;
typedef __bf16 bf16x4 __attribute__((ext_vector_type(4)));
typedef __bf16 bf16x8 __attribute__((ext_vector_type(8)));
typedef float  f32x4  __attribute__((ext_vector_type(4)));

#define TOKENS 16384
#define D_IN   4096
#define D_OUT  4096
#define RANK   512

// Async global->LDS, 16B per lane. LDS dest wave-uniform base + lane*16;
// global SOURCE is per-lane (swizzles applied by permuting the source).
__device__ inline void gload_lds16(const void* g, void* l) {
    __builtin_amdgcn_global_load_lds((const __attribute__((address_space(1))) void*)g,
                                     (__attribute__((address_space(3))) void*)l,
                                     16, 0, 0);
}

// ---------------------------------------------------------------------------
// Prep 1: Vst[r][k'] = bf16(V[k][r] * sigma[r]), PRE-SWIZZLED for GEMM1
//   (verified r3/r4: conflicts -> 0). Within each 64-k block: k -> k^((r&7)<<3).
// ---------------------------------------------------------------------------
__global__ __launch_bounds__(256) void vt_scale(const float* __restrict__ V,
                                                const float* __restrict__ sg,
                                                bf16* __restrict__ Vst) {
    __shared__ float tile[64][65];
    const int tx = threadIdx.x & 63;
    const int ty = threadIdx.x >> 6;
    const int kb = blockIdx.x * 64;
    const int rb = blockIdx.y * 64;
    const float s = sg[rb + tx];
#pragma unroll
    for (int i = ty; i < 64; i += 4)
        tile[i][tx] = V[(size_t)(kb + i) * RANK + rb + tx] * s;
    __syncthreads();
#pragma unroll
    for (int i = ty; i < 64; i += 4) {
        int r = rb + i;
        int kp = kb + (tx ^ ((r & 7) << 3));
        Vst[(size_t)r * D_IN + kp] = (bf16)tile[tx][i];
    }
}

// ---------------------------------------------------------------------------
// Prep 2: Ub[n][k'] = bf16(U[n][k]), PRE-SWIZZLED for GEMM2's B staging:
//   within each 64-k block, 8-elem chunk q -> q ^ (n&7). One chunk per thread.
// ---------------------------------------------------------------------------
__global__ __launch_bounds__(256) void cvt_u_swz(const float* __restrict__ U,
                                                 bf16* __restrict__ Ub) {
    int g = blockIdx.x * 256 + threadIdx.x;      // chunk id (8 elems each)
    int n = g >> 6;                              // row (RANK/8 = 64 chunks/row)
    int c = g & 63;
    int blk = c >> 3, q = c & 7;
    const float* src = U + (size_t)n * RANK + c * 8;
    f32x4 v0 = *(const f32x4*)src;
    f32x4 v1 = *(const f32x4*)(src + 4);
    bf16x8 b;
    b[0] = (bf16)v0[0]; b[1] = (bf16)v0[1]; b[2] = (bf16)v0[2]; b[3] = (bf16)v0[3];
    b[4] = (bf16)v1[0]; b[5] = (bf16)v1[1]; b[6] = (bf16)v1[2]; b[7] = (bf16)v1[3];
    *(bf16x8*)(Ub + (size_t)n * RANK + blk * 64 + ((q ^ (n & 7)) * 8)) = b;
}

// ---------------------------------------------------------------------------
// GEMM1 (r8 structure, 155 µs control): T = bf16( A_f32 @ B_bf16^T ).
//   A staged f32 via global_load_lds, cvt at frag read. ONLY change vs r8:
//   the T-write pre-swizzles each 64-col block (chunk ^ (row&7)) so GEMM2's
//   linear gload_lds staging lands T swizzled in LDS (rule-21 source swizzle).
// ---------------------------------------------------------------------------
__device__ inline bf16x8 cvt8(f32x4 a, f32x4 b) {
    bf16x8 r;
    r[0] = (bf16)a[0]; r[1] = (bf16)a[1]; r[2] = (bf16)a[2]; r[3] = (bf16)a[3];
    r[4] = (bf16)b[0]; r[5] = (bf16)b[1]; r[6] = (bf16)b[2]; r[7] = (bf16)b[3];
    return r;
}

__global__ __launch_bounds__(256) void gemm1_alds(const float* __restrict__ A,
                                                  const bf16* __restrict__ B,
                                                  bf16* __restrict__ T,
                                                  int M, int N, int K) {
    __shared__ float Afl[128 * 64];
    __shared__ bf16  Bl[128 * 64];

    const int t  = threadIdx.x;
    const int l  = t & 63;
    const int w  = t >> 6;
    const int wr = w >> 1, wc = w & 1;
    const int lr = l & 15;
    const int kg = l >> 4;
    const int sxorB = (lr & 7) << 3;

    const int nwg = gridDim.x;
    const int bid = blockIdx.x;
    const int cpx = nwg >> 3;
    const int swz = (bid & 7) * cpx + (bid >> 3);
    const int ntn = N >> 7;
    const int tm  = (swz / ntn) << 7;
    const int tn  = (swz % ntn) << 7;

    const int arow = t >> 4;
    const int acr  = t & 15;
    const float* Asrc = A + (size_t)(tm + arow) * K + ((acr ^ arow) << 2);
    const bf16* Bp = B + (size_t)(tn + (t >> 3)) * K + (t & 7) * 8;

    f32x4 acc[4][4] = {};

    for (int kt = 0; kt < K; kt += 64) {
#pragma unroll
        for (int c = 0; c < 8; ++c)
            gload_lds16(Asrc + kt + (size_t)(c * 16) * K, &Afl[(c * 256 + t) * 4]);
#pragma unroll
        for (int c = 0; c < 4; ++c)
            gload_lds16(Bp + kt + (size_t)(c * 32) * K, &Bl[(c * 256 + t) * 8]);
        __syncthreads();

#pragma unroll
        for (int ks = 0; ks < 2; ++ks) {
            bf16x8 af[4], bfr[4];
            const int q0 = ks * 8 + kg * 2;
#pragma unroll
            for (int f = 0; f < 4; ++f) {
                const float* Arow = &Afl[(wr * 64 + f * 16 + lr) * 64];
                f32x4 h0 = *(const f32x4*)&Arow[(q0 ^ lr) << 2];
                f32x4 h1 = *(const f32x4*)&Arow[((q0 + 1) ^ lr) << 2];
                af[f] = cvt8(h0, h1);
                bfr[f] = *(const bf16x8*)&Bl[(wc * 64 + f * 16 + lr) * 64 +
                                             ((ks * 32 + kg * 8) ^ sxorB)];
            }
#pragma unroll
            for (int fm = 0; fm < 4; ++fm)
#pragma unroll
                for (int fn = 0; fn < 4; ++fn)
                    acc[fm][fn] = __builtin_amdgcn_mfma_f32_16x16x32_bf16(
                        af[fm], bfr[fn], acc[fm][fn], 0, 0, 0);
        }
        __syncthreads();
    }

    // C-write, PRE-SWIZZLED for GEMM2: col ^= ((row&7)<<3) within 64-block.
    const int r0 = tm + wr * 64 + kg * 4;
    const int c0 = tn + wc * 64 + lr;
#pragma unroll
    for (int fm = 0; fm < 4; ++fm)
#pragma unroll
        for (int fn = 0; fn < 4; ++fn)
#pragma unroll
            for (int r = 0; r < 4; ++r) {
                int row = r0 + fm * 16 + r;
                int col = (c0 + fn * 16) ^ ((row & 7) << 3);
                T[(size_t)row * N + col] = (bf16)acc[fm][fn][r];
            }
}

// ---------------------------------------------------------------------------
// GEMM2 — 256x256 multi-phase counted pipeline (T3+T4+T2+T5):
//   512 thr = 8 waves (2M x 4N), wave tile 128x64 (8x4 frags 16x16x32).
//   2-dbuf 128 KB LDS. Per K-tile: 4 quadrant phases with NO barriers
//   (LDS read-only between stages) -> 64 MFMA/wave per 2 barriers; stage
//   one tile ahead; steady-state wait vmcnt(8), NEVER 0 until tail.
//   A (=T) and B (=Ub) are pre-swizzled in HBM; frag reads XOR (lr&7)<<3.
// ---------------------------------------------------------------------------
__global__ __launch_bounds__(512, 2) void gemm2_8p(const bf16* __restrict__ A,
                                                   const bf16* __restrict__ B,
                                                   float* __restrict__ out,
                                                   int M, int N, int K) {
    __shared__ bf16 Al[2][256 * 64];   // 32 KB each
    __shared__ bf16 Bl[2][256 * 64];   // 32 KB each  -> 128 KB total

    const int t   = threadIdx.x;       // 0..511
    const int l   = t & 63;
    const int wid = t >> 6;
    const int wm  = wid >> 2;          // 0..1
    const int wn  = wid & 3;           // 0..3
    const int lr  = l & 15;
    const int kg  = l >> 4;
    const int sxor = (lr & 7) << 3;

    // XCD-aware bijective swizzle (nwg=1024, %8==0)
    const int nwg = gridDim.x;
    const int bid = blockIdx.x;
    const int cpx = nwg >> 3;
    const int swz = (bid & 7) * cpx + (bid >> 3);
    const int ntn = N >> 8;            // 16
    const int tm  = (swz / ntn) << 8;
    const int tn  = (swz % ntn) << 8;

    // staging: 4 loads each for A,B; row = c*64 + (t>>3), chunk t&7 (src preswz)
    const bf16* Apt = A + (size_t)(tm + (t >> 3)) * K + (t & 7) * 8;
    const bf16* Bpt = B + (size_t)(tn + (t >> 3)) * K + (t & 7) * 8;
    const int ldst = t * 8;

    const int NT = K >> 6;             // 8

    f32x4 acc[8][4] = {};
    bf16x8 aq[4][2], bq[2][2];

#define STAGE(BUF, KT)                                                         \
    _Pragma("unroll") for (int c = 0; c < 4; ++c) {                            \
        gload_lds16(Apt + (KT) + (size_t)(c * 64) * K, &Al[BUF][c * 4096 + ldst]); \
        gload_lds16(Bpt + (KT) + (size_t)(c * 64) * K, &Bl[BUF][c * 4096 + ldst]); \
    }

#define RD_A(BUF, QM)                                                          \
    _Pragma("unroll") for (int f = 0; f < 4; ++f)                              \
    _Pragma("unroll") for (int ks = 0; ks < 2; ++ks)                           \
        aq[f][ks] = *(const bf16x8*)&Al[BUF][(wm * 128 + (QM) * 64 + f * 16 + lr) * 64 + \
                                            ((ks * 32 + kg * 8) ^ sxor)];

#define RD_B(BUF, QN)                                                          \
    _Pragma("unroll") for (int f = 0; f < 2; ++f)                              \
    _Pragma("unroll") for (int ks = 0; ks < 2; ++ks)                           \
        bq[f][ks] = *(const bf16x8*)&Bl[BUF][(wn * 64 + (QN) * 32 + f * 16 + lr) * 64 + \
                                            ((ks * 32 + kg * 8) ^ sxor)];

#define MM(QM, QN)                                                             \
    __builtin_amdgcn_s_setprio(1);                                             \
    _Pragma("unroll") for (int ks = 0; ks < 2; ++ks)                           \
    _Pragma("unroll") for (int fm = 0; fm < 4; ++fm)                           \
    _Pragma("unroll") for (int fn = 0; fn < 2; ++fn)                           \
        acc[(QM) * 4 + fm][(QN) * 2 + fn] = __builtin_amdgcn_mfma_f32_16x16x32_bf16( \
            aq[fm][ks], bq[fn][ks], acc[(QM) * 4 + fm][(QN) * 2 + fn], 0, 0, 0); \
    __builtin_amdgcn_s_setprio(0);

    // ---- prologue: stage tiles 0 and 1; wait tile 0 only (vmcnt(8)) ----
    STAGE(0, 0);
    STAGE(1, 64);
    asm volatile("s_waitcnt vmcnt(8)" ::: "memory");
    __builtin_amdgcn_sched_barrier(0);
    __builtin_amdgcn_s_barrier();
    __builtin_amdgcn_sched_barrier(0);

    for (int i = 0; i < NT; ++i) {
        const int p = i & 1;
        // ---- 4 quadrant phases, no barriers (LDS read-only here) ----
        RD_A(p, 0); RD_B(p, 0); MM(0, 0);
        RD_B(p, 1);             MM(0, 1);
        RD_A(p, 1); RD_B(p, 0); MM(1, 0);
        RD_B(p, 1);             MM(1, 1);

        if (i + 1 < NT) {
            __builtin_amdgcn_sched_barrier(0);
            __builtin_amdgcn_s_barrier();      // all waves done reading buf p
            __builtin_amdgcn_sched_barrier(0);
            if (i + 2 < NT) {
                STAGE(p, (i + 2) * 64);        // refill freed buffer
                asm volatile("s_waitcnt vmcnt(8)" ::: "memory");  // tile i+1 landed
            } else {
                asm volatile("s_waitcnt vmcnt(0)" ::: "memory");  // tail drain
            }
            __builtin_amdgcn_sched_barrier(0);
            __builtin_amdgcn_s_barrier();      // publish buf p^1
            __builtin_amdgcn_sched_barrier(0);
        }
    }

    // ---- epilogue: col = lane&15, row = (lane>>4)*4 + reg ----
    const int r0 = tm + wm * 128 + kg * 4;
    const int c0 = tn + wn * 64 + lr;
#pragma unroll
    for (int fm = 0; fm < 8; ++fm)
#pragma unroll
        for (int fn = 0; fn < 4; ++fn)
#pragma unroll
            for (int r = 0; r < 4; ++r)
                out[(size_t)(r0 + fm * 16 + r) * N + (c0 + fn * 16)] = acc[fm][fn][r];

#undef STAGE
#undef RD_A
#undef RD_B
#undef MM
}

// ---------------------------------------------------------------------------
extern "C" void kernel_launch(void* const* d_in, const int* in_sizes, int n_in,
                              void* d_out, int out_size, void* d_ws, size_t ws_size,
                              hipStream_t stream) {
    const float* x  = (const float*)d_in[0];  // [16384][4096]
    const float* U  = (const float*)d_in[1];  // [4096][512]
    const float* sg = (const float*)d_in[2];  // [512]
    const float* V  = (const float*)d_in[3];  // [4096][512]
    float* out = (float*)d_out;               // [16384][4096] f32

    char* ws = (char*)d_ws;
    bf16* Vst = (bf16*)ws;                    // [512][4096]  = 4 MB (pre-swizzled)
    bf16* Ub  = (bf16*)(ws + (4u << 20));     // [4096][512]  = 4 MB (pre-swizzled)
    bf16* T   = (bf16*)(ws + (8u << 20));     // [16384][512] = 16 MB (pre-swizzled)

    vt_scale<<<dim3(D_IN / 64, RANK / 64), 256, 0, stream>>>(V, sg, Vst);
    cvt_u_swz<<<(D_OUT * RANK / 8) / 256, 256, 0, stream>>>(U, Ub);

    // GEMM1: T = bf16( x @ Vst^T ), grid 512 (155 µs control)
    gemm1_alds<<<(TOKENS / 128) * (RANK / 128), 256, 0, stream>>>(
        x, Vst, T, TOKENS, RANK, D_IN);

    // GEMM2: out = T @ Ub^T (f32), 256x256 counted pipeline, grid 1024
    gemm2_8p<<<(TOKENS / 256) * (D_OUT / 256), 512, 0, stream>>>(
        T, Ub, out, TOKENS, D_OUT, RANK);
}